// Round 13
// baseline (1647.335 us; speedup 1.0000x reference)
//
#include <hip/hip_runtime.h>
#include <math.h>

// Soft-DTW (gamma=0.1), 4096x4096, wave-parallel band pipeline v5.
// Topology = v2 (fastest so far): 64 WGs x 1 wave; band b = rows [64b,64b+63],
// lane l = row 64b+l, lane l at step t computes cell (row, t-l).
// v5 core change: the per-step dependency chain (measured ~300-350 cy across
// v1-v4, dominated by serial v_exp->v_log transcendentals) is rebuilt in
// (P,S) form: R' = P - log2(S).  softmin':
//   mu = min3(P_up, P_diag, P_left)            (pivot; exact softmin algebra)
//   S  = e_up*S_up + e_dg*S_dg + e_lf*S_lf,  e_nb = exp2(mu - P_nb)
//   P  = d' + mu
// -> log2 is GONE from the chain (only at handoff/epilogue, off-chain), and
// exp2 is a 5-FMA polynomial (rndne + poly + ldexp), no trans-pipe latency.
// S in [0.5, 3^16] within a chunk (S_new >= min neighbor S >= 0.5; <= 3^16);
// exact power-of-2 renorm (frexp/ldexp) each 16-step chunk.
// Handoff format unchanged from v2 (exact R' row, value-as-flag vs 0xAA).

#define KS     14.426950408889634f   // 1/(0.1*ln2)
#define BIGP   1.4426950e+11f        // 1e10 * KS
#define NN     4096
#define POISON 0xAAAAAAAAu           // ws poison; R' rows are > 0, never this
#define YPADF  64
#define YPADB  192
#define YTOT   (YPADF + NN + YPADB)  // 4352 floats

__device__ __forceinline__ float dpp_shr1(float oldv, float src) {
    // lanes 1..63 <- src[lane-1]; lane 0 keeps oldv (bound_ctrl=false)
    int o = __float_as_int(oldv), s = __float_as_int(src);
    return __int_as_float(__builtin_amdgcn_update_dpp(o, s, 0x138 /*wave_shr:1*/, 0xF, 0xF, false));
}
__device__ __forceinline__ float rdlane(float v, int l) {
    return __int_as_float(__builtin_amdgcn_readlane(__float_as_int(v), l));
}
__device__ __forceinline__ float aload(const float* p) {
    unsigned u = __hip_atomic_load((const unsigned*)p, __ATOMIC_RELAXED, __HIP_MEMORY_SCOPE_AGENT);
    return __uint_as_float(u);
}
__device__ __forceinline__ void astore(float* p, float v) {
    __hip_atomic_store((unsigned*)p, __float_as_uint(v), __ATOMIC_RELAXED, __HIP_MEMORY_SCOPE_AGENT);
}
// exp2 via deg-5 polynomial: rndne range-reduce, |f|<=0.5, err ~2.4e-6.
// No v_exp_f32 -> no trans-pipe latency on the chain.
__device__ __forceinline__ float exp2p(float a) {
    a = fmaxf(a, -150.0f);                    // BIG paths -> ldexp underflow -> 0
    float n = rintf(a);                       // v_rndne_f32
    float f = a - n;                          // [-0.5, 0.5]
    float p = fmaf(f, 0.00133335581464f, 0.00961812910763f);
    p = fmaf(f, p, 0.0555041086648f);
    p = fmaf(f, p, 0.240226506959f);
    p = fmaf(f, p, 0.693147180560f);
    p = fmaf(f, p, 1.0f);
    return ldexpf(p, (int)n);                 // v_ldexp_f32
}

__global__ __launch_bounds__(64, 1)
void sdtw_kernel(const float* __restrict__ x, const float* __restrict__ y,
                 float* __restrict__ out, float* __restrict__ bnd) {
    __shared__ float shy[YTOT];               // y*sqrt(K), zero-padded
    const int band = blockIdx.x;
    const int lane = threadIdx.x;
    const float sqK = sqrtf(KS);

    for (int i = lane; i < YTOT; i += 64) {
        int yi = i - YPADF;
        shy[i] = (yi >= 0 && yi < NN) ? y[yi] * sqK : 0.0f;
    }
    __syncthreads();

    const float xs = x[band * 64 + lane] * sqK;
    float* bnd_my         = bnd + band * NN;
    const float* bnd_prev = bnd + (band > 0 ? band - 1 : 0) * NN;
    const bool prod = (band < 63);
    const bool cons = (band > 0);

    // (P,S) state: left = (Pp,Sp) at t-1; diag = (Pd,Sd) = prev shifted-up
    float Pp = BIGP, Sp = 1.0f;
    float Pd = (band == 0 && lane == 0) ? 0.0f : BIGP, Sd = 1.0f;  // virtual R[0,0]=0
    float rsP = 0.0f, rsS = 1.0f;
    float yw[16], ywn[16];
    float bcur = 0.0f, bnext = 0.0f;

    #pragma unroll
    for (int k = 0; k < 16; ++k) yw[k] = shy[YPADF + k - lane];
    if (cons) bcur = aload(&bnd_prev[lane & 15]);

    for (int c = 0; c < 260; ++c) {                     // 260*16 = 4160 steps
        const int base = c * 16;
        if (cons && c <= 255) {                         // value-as-flag poll
            int bail = 0;
            while ((__ballot(__float_as_uint(bcur) != POISON) & 0xFFFFull) != 0xFFFFull) {
                __builtin_amdgcn_s_sleep(1);
                bcur = aload(&bnd_prev[base + (lane & 15)]);
                if (++bail > (1 << 20)) break;
            }
        }
        if (cons && c < 255) bnext = aload(&bnd_prev[base + 16 + (lane & 15)]);
        {
            const float* yb = shy + YPADF + base + 16 - lane;
            #pragma unroll
            for (int k = 0; k < 16; ++k) ywn[k] = yb[k];
        }
        // ---- 16 DP steps in (P,S) form ------------------------------------
        #pragma unroll
        for (int s = 0; s < 16; ++s) {
            float binj = cons ? rdlane(bcur, s) : BIGP; // boundary R' (S=1)
            float PU = dpp_shr1(binj, Pp);              // up = (i-1, j)
            float SU = dpp_shr1(1.0f, Sp);
            float mu = fminf(fminf(PU, Pd), Pp);        // min3 pivot
            float eU = exp2p(mu - PU);
            float eD = exp2p(mu - Pd);
            float eL = exp2p(mu - Pp);
            float Sn = fmaf(eU, SU, fmaf(eD, Sd, eL * Sp));
            float diff = xs - yw[s];
            float Pn = fmaf(diff, diff, mu);            // P = d' + mu
            if (prod) {                                 // exact R' handoff (off-chain)
                float rh = Pn - __builtin_amdgcn_logf(Sn);   // log2
                const int t = base + s;
                if (lane == 63 && t >= 63 && t <= 63 + NN - 1)
                    astore(&bnd_my[t - 63], rh);
            }
            Pd = PU; Sd = SU; Pp = Pn; Sp = Sn;
            if (c == 259 && s == 14) { rsP = Pn; rsS = Sn; } // t=4158 = (4095,4095)
        }
        // ---- exact power-of-2 renorm (keeps S in [0.5,1) at chunk start) --
        {
            int e1, e2;
            float m1 = frexpf(Sp, &e1); Sp = m1; Pp -= (float)e1;
            float m2 = frexpf(Sd, &e2); Sd = m2; Pd -= (float)e2;
        }
        bcur = bnext;
        #pragma unroll
        for (int k = 0; k < 16; ++k) yw[k] = ywn[k];
    }

    if (band == 63 && lane == 63)
        out[0] = fabsf((rsP - __builtin_amdgcn_logf(rsS)) * (1.0f / KS));
}

extern "C" void kernel_launch(void* const* d_in, const int* in_sizes, int n_in,
                              void* d_out, int out_size, void* d_ws, size_t ws_size,
                              hipStream_t stream) {
    const float* x = (const float*)d_in[0];   // "inputs"  (rows)
    const float* y = (const float*)d_in[1];   // "targets" (cols)
    float* out = (float*)d_out;
    float* bnd = (float*)d_ws;                // 63 used rows * 16 KiB ~= 1 MiB
    sdtw_kernel<<<dim3(64), dim3(64), 0, stream>>>(x, y, out, bnd);
}